// Round 10
// baseline (399.595 us; speedup 1.0000x reference)
//
#include <hip/hip_runtime.h>
#include <hip/hip_bf16.h>
#include <hip/hip_fp16.h>

#define NB 4
#define NN 20000
#define NE 320000
#define IND 21
#define ED 64
#define H2 128
#define CAP 48
#define NRANGE 32
#define RNODES 625       // 32 * 625 = 20000
#define BINCAP 160       // compact LDS bin capacity (exp 64, 12 sigma)
#define SCAP 11264       // staging cap per (graph,range): exp 10000, 12 sigma
#define BN_EPS 1e-5f

typedef __attribute__((ext_vector_type(8))) short bf16x8;
typedef __attribute__((ext_vector_type(4))) float f32x4;

__device__ __forceinline__ short f2bf(float f) {
    unsigned u = __float_as_uint(f);
    u += 0x7fffu + ((u >> 16) & 1u);   // RNE
    return (short)(u >> 16);
}

__device__ __forceinline__ void add8(float* ac, const uint4 rv) {
    const float2 f0 = __half22float2(*(const __half2*)&rv.x);
    const float2 f1 = __half22float2(*(const __half2*)&rv.y);
    const float2 f2 = __half22float2(*(const __half2*)&rv.z);
    const float2 f3 = __half22float2(*(const __half2*)&rv.w);
    ac[0] += f0.x; ac[1] += f0.y; ac[2] += f1.x; ac[3] += f1.y;
    ac[4] += f2.x; ac[5] += f2.y; ac[6] += f3.x; ac[7] += f3.y;
}

// ---------------- setup kernels ----------------

// Phase A: coalesced pass over edges; LDS-bin into 32 dst-ranges (625 nodes);
// bulk-copy compact records (lo = src|bf16attr, hi = dst) to staging.
__global__ __launch_bounds__(256) void k_compact(
    const int* __restrict__ ei, const float* __restrict__ eattr,
    uint2* __restrict__ stage, int* __restrict__ rcnt)
{
    __shared__ uint2 bins[NRANGE][BINCAP];   // 40 KB
    __shared__ int lcnt[NRANGE];
    __shared__ int lbase[NRANGE];
    const int b = blockIdx.y;
    const int e0 = blockIdx.x * 2048;
    const int tid = threadIdx.x;
    if (tid < NRANGE) lcnt[tid] = 0;
    __syncthreads();
    const int* srcp = ei + (size_t)b * 2 * NE;
    const int* dstp = srcp + NE;
    const float* ap = eattr + (size_t)b * NE;
    #pragma unroll
    for (int it = 0; it < 8; ++it) {
        const int e = e0 + it * 256 + tid;
        if (e < NE) {
            const int dst = dstp[e];
            const int src = srcp[e];
            const float a = ap[e];
            const int r = dst / RNODES;
            const unsigned lo = ((unsigned)src & 0xffffu) | (__float_as_uint(a) & 0xffff0000u);
            const int p = atomicAdd(&lcnt[r], 1);
            if (p < BINCAP) bins[r][p] = make_uint2(lo, (unsigned)dst);
        }
    }
    __syncthreads();
    if (tid < NRANGE) lbase[tid] = atomicAdd(&rcnt[b * NRANGE + tid], min(lcnt[tid], BINCAP));
    __syncthreads();
    for (int r = 0; r < NRANGE; ++r) {
        const int c = min(lcnt[r], BINCAP);
        uint2* dstg = stage + (size_t)(b * NRANGE + r) * SCAP + lbase[r];
        for (int i = tid; i < c; i += 256) dstg[i] = bins[r][i];
    }
}

// Phase B: SINGLE-WRITER scatter. One block per (graph,range): its bucket
// slice + cnt slice are touched by this block only -> lines live in one L2,
// written back once (R9: this removed the 47 MB write-through).
__global__ __launch_bounds__(256) void k_scatter(
    const uint2* __restrict__ stage, const int* __restrict__ rcnt,
    int* __restrict__ cnt, unsigned int* __restrict__ bucket)
{
    const int b = blockIdx.x >> 5;
    const int g = blockIdx.x & 31;
    const int count = min(rcnt[b * NRANGE + g], SCAP);
    const uint2* st = stage + (size_t)(b * NRANGE + g) * SCAP;
    for (int idx = threadIdx.x; idx < count; idx += 256) {
        const uint2 rec = st[idx];
        const int node = b * NN + (int)rec.y;
        const int p = atomicAdd(&cnt[node], 1);
        if (p < CAP) bucket[(size_t)node * CAP + p] = rec.x;
    }
}

// h0 = x @ inW + inb, stored fp16 (gather-only consumer)
__global__ __launch_bounds__(256) void k_in(
    const float* __restrict__ x, const float* __restrict__ inW,
    const float* __restrict__ inb, __half* __restrict__ h)
{
    const int b = blockIdx.y;
    const int t = blockIdx.x * 256 + threadIdx.x;
    const int n = t >> 6;
    const int c = t & 63;
    if (n >= NN) return;
    const float* xr = x + ((size_t)b * NN + n) * IND;
    float acc = inb[c];
    #pragma unroll
    for (int k = 0; k < IND; ++k) acc += xr[k] * inW[k * ED + c];
    h[((size_t)b * NN + n) * ED + c] = __float2half(acc);
}

// Per-layer weight conversion (bf16, B-fragment layout), uv fold, stats zero.
__global__ __launch_bounds__(256) void k_prep(
    const float* __restrict__ W1, const float* __restrict__ W2,
    const float* __restrict__ edgeW, const float* __restrict__ edgeb,
    short* __restrict__ W1T, short* __restrict__ W2T,
    float* __restrict__ uv_all, float* __restrict__ stats_all)
{
    const int l = blockIdx.x;
    const int tid = threadIdx.x;
    ((float4*)(stats_all + l * 1024))[tid] = make_float4(0.f, 0.f, 0.f, 0.f);
    for (int i = tid; i < H2 * ED; i += 256) {
        const int j = i >> 6, k = i & 63;
        W1T[l * 8192 + i] = f2bf(W1[(size_t)l * H2 * H2 + k * H2 + j]);
    }
    for (int i = tid; i < ED * H2; i += 256) {
        const int c = i >> 7, k = i & 127;
        W2T[l * 8192 + i] = f2bf(W2[(size_t)l * H2 * ED + k * ED + c]);
    }
    if (tid < H2) {
        float u = 0.f, v = 0.f;
        for (int k = 0; k < ED; ++k) {
            const float w = W1[(size_t)l * H2 * H2 + (ED + k) * H2 + tid];
            u += edgeW[l * ED + k] * w;
            v += edgeb[l * ED + k] * w;
        }
        uv_all[l * 256 + tid] = u;
        uv_all[l * 256 + H2 + tid] = v;
    }
}

// ---------------- per-layer kernels ----------------

// FUSED gather + MFMA W1-top GEMM + BN stats. 16 nodes/block, 5000 blocks.
// R10: bucket rows staged to LDS coalescedly; 16 lanes/node (8 channels x
// 2 edge-halves, shfl-combined); W1T B-fragments loaded direct from global
// (L2-hot) -> no weight staging, LDS ~8 KB.
__global__ __launch_bounds__(256) void k_aggr_stats(
    const __half* __restrict__ h, const unsigned int* __restrict__ bucket,
    const int* __restrict__ cnt_arr, const short* __restrict__ W1Tl,
    const float* __restrict__ b1l, const float* __restrict__ uv_l,
    short* __restrict__ aggr_bf, float* __restrict__ s_attr,
    float* __restrict__ stats_l, int write_sattr)
{
    __shared__ unsigned int brow[16 * CAP];   // 3 KB
    __shared__ short atb[16 * 72];            // 2.25 KB
    __shared__ float sdl[16], ddl[16];
    __shared__ float uL[H2], vL[H2], bbL[H2];
    const int tid = threadIdx.x;
    const int g = blockIdx.x & 7;
    const int b = g >> 1;
    const int t = ((int)blockIdx.x >> 3) * 2 + (g & 1);   // 0..1249
    const int n0 = t * 16;

    const int l = tid & 63;
    const int w = tid >> 6;
    const int m = l & 15, quad = l >> 4;

    // B fragments direct from global (independent of everything; issue early)
    bf16x8 fb[2][2];
    #pragma unroll
    for (int t2 = 0; t2 < 2; ++t2)
        #pragma unroll
        for (int kc = 0; kc < 2; ++kc)
            fb[t2][kc] = *(const bf16x8*)&W1Tl[((w * 2 + t2) * 16 + m) * 64 + kc * 32 + quad * 8];

    if (tid < H2) { uL[tid] = uv_l[tid]; vL[tid] = uv_l[H2 + tid]; bbL[tid] = b1l[tid]; }

    // coalesced bucket-row stage: 16 nodes x 48 slots = 768 words
    {
        const unsigned int* bsrc = bucket + (size_t)(b * NN + n0) * CAP;
        #pragma unroll
        for (int i = tid; i < 16 * CAP; i += 256) brow[i] = bsrc[i];
    }
    __syncthreads();

    // gather: 16 lanes/node (q = channel octet, eh = edge half)
    {
        const int node = tid >> 4;
        const int sub = tid & 15;
        const int q = sub & 7, eh = sub >> 3;
        const int cntraw = cnt_arr[b * NN + n0 + node];
        const int cnt = min(cntraw, CAP);
        const int hcnt = (cnt + 1) >> 1;
        const int j1 = eh ? cnt : hcnt;
        const unsigned int* row = &brow[node * CAP];
        const __half* hp = h + (size_t)b * NN * ED + q * 8;
        float ac[8];
        #pragma unroll
        for (int i = 0; i < 8; ++i) ac[i] = 0.f;
        float sa = 0.f;
        int j = eh ? hcnt : 0;
        for (; j + 4 <= j1; j += 4) {
            const unsigned e0 = row[j], e1 = row[j + 1], e2 = row[j + 2], e3 = row[j + 3];
            const uint4 r0 = *(const uint4*)(hp + (size_t)(e0 & 0xffffu) * ED);
            const uint4 r1 = *(const uint4*)(hp + (size_t)(e1 & 0xffffu) * ED);
            const uint4 r2 = *(const uint4*)(hp + (size_t)(e2 & 0xffffu) * ED);
            const uint4 r3 = *(const uint4*)(hp + (size_t)(e3 & 0xffffu) * ED);
            sa += __uint_as_float(e0 & 0xffff0000u) + __uint_as_float(e1 & 0xffff0000u)
                + __uint_as_float(e2 & 0xffff0000u) + __uint_as_float(e3 & 0xffff0000u);
            add8(ac, r0); add8(ac, r1); add8(ac, r2); add8(ac, r3);
        }
        for (; j < j1; ++j) {
            const unsigned e = row[j];
            sa += __uint_as_float(e & 0xffff0000u);
            const uint4 r0 = *(const uint4*)(hp + (size_t)(e & 0xffffu) * ED);
            add8(ac, r0);
        }
        // combine the two edge-halves (lane ^ 8)
        #pragma unroll
        for (int i = 0; i < 8; ++i) ac[i] += __shfl_xor(ac[i], 8);
        sa += __shfl_xor(sa, 8);
        if (eh == 0) {
            uint4 pk;
            pk.x = (unsigned short)f2bf(ac[0]) | ((unsigned int)(unsigned short)f2bf(ac[1]) << 16);
            pk.y = (unsigned short)f2bf(ac[2]) | ((unsigned int)(unsigned short)f2bf(ac[3]) << 16);
            pk.z = (unsigned short)f2bf(ac[4]) | ((unsigned int)(unsigned short)f2bf(ac[5]) << 16);
            pk.w = (unsigned short)f2bf(ac[6]) | ((unsigned int)(unsigned short)f2bf(ac[7]) << 16);
            *(uint4*)&atb[node * 72 + q * 8] = pk;
            *(uint4*)&aggr_bf[((size_t)b * NN + n0 + node) * ED + q * 8] = pk;
        }
        if (sub == 0) {
            sdl[node] = sa;
            ddl[node] = (float)cntraw;
            if (write_sattr) s_attr[b * NN + n0 + node] = sa;
        }
    }
    __syncthreads();

    // MFMA: C[16 nodes x 128 j]; wave w handles j-tiles 2w, 2w+1
    f32x4 acc0 = {0.f, 0.f, 0.f, 0.f}, acc1 = {0.f, 0.f, 0.f, 0.f};
    #pragma unroll
    for (int kc = 0; kc < 2; ++kc) {
        const bf16x8 fa = *(const bf16x8*)&atb[m * 72 + kc * 32 + quad * 8];
        acc0 = __builtin_amdgcn_mfma_f32_16x16x32_bf16(fa, fb[0][kc], acc0, 0, 0, 0);
        acc1 = __builtin_amdgcn_mfma_f32_16x16x32_bf16(fa, fb[1][kc], acc1, 0, 0, 0);
    }
    float sa_r[4], dg_r[4];
    #pragma unroll
    for (int r = 0; r < 4; ++r) { sa_r[r] = sdl[quad * 4 + r]; dg_r[r] = ddl[quad * 4 + r]; }
    #pragma unroll
    for (int t2 = 0; t2 < 2; ++t2) {
        const int j = (w * 2 + t2) * 16 + m;
        const float u = uL[j], v = vL[j], bb = bbL[j];
        float ls = 0.f, lq = 0.f;
        #pragma unroll
        for (int r = 0; r < 4; ++r) {
            const float h1 = (t2 ? acc1[r] : acc0[r]) + sa_r[r] * u + dg_r[r] * v + bb;
            ls += h1; lq += h1 * h1;
        }
        ls += __shfl_xor(ls, 16); ls += __shfl_xor(ls, 32);
        lq += __shfl_xor(lq, 16); lq += __shfl_xor(lq, 32);
        if (l < 16) {
            atomicAdd(&stats_l[b * H2 + j], ls);
            atomicAdd(&stats_l[NB * H2 + b * H2 + j], lq);
        }
    }
}

// Out pass, 64 nodes/block, fused BN finalize. R10: A and B fragments loaded
// direct from global (aggr_bf rows / W1T / W2T are L2-hot) -> only the
// P-matrix transit (C-layout -> A-layout) uses LDS. LDS ~20 KB.
__global__ __launch_bounds__(256) void k_mlp_out(
    const short* __restrict__ aggr_bf, const float* __restrict__ s_attr,
    const int* __restrict__ cnt_arr, const short* __restrict__ W1Tl,
    const short* __restrict__ W2Tl, const float* __restrict__ b1l,
    const float* __restrict__ uv_l, const float* __restrict__ stats_l,
    const float* __restrict__ gamma_l, const float* __restrict__ beta_l,
    const float* __restrict__ b2l, __half* __restrict__ outh,
    float* __restrict__ outf, int last)
{
    __shared__ short pb[64 * 136];    // 17 KB
    __shared__ float sdl[64], ddl[64];
    __shared__ float uL[H2], vL[H2], bbL[H2], scL[H2], shL[H2];
    const int tid = threadIdx.x;
    const int g = blockIdx.x & 7;
    const int b = g >> 1;
    const int t = ((int)blockIdx.x >> 3) * 2 + (g & 1);
    if (t >= (NN + 63) / 64) return;
    const int n0 = t * 64;

    const int l = tid & 63;
    const int w = tid >> 6;
    const int m = l & 15, quad = l >> 4;

    if (tid < 64) sdl[tid] = s_attr[b * NN + min(n0 + tid, NN - 1)];
    else if (tid < 128) ddl[tid - 64] = (float)cnt_arr[b * NN + min(n0 + tid - 64, NN - 1)];
    if (tid < H2) {
        const int j = tid;
        const float mm = stats_l[b * H2 + j] * (1.f / NN);
        const float var = fmaxf(stats_l[NB * H2 + b * H2 + j] * (1.f / NN) - mm * mm, 0.f);
        const float rs = rsqrtf(var + BN_EPS);
        const float sc = gamma_l[j] * rs;
        scL[j] = sc;
        shL[j] = beta_l[j] - mm * sc;
        uL[j] = uv_l[j]; vL[j] = uv_l[H2 + j]; bbL[j] = b1l[j];
    }

    // A fragments (16 nodes of m-tile w), rows clamped for the tail block
    const int rn = min(n0 + w * 16 + m, NN - 1);
    bf16x8 fa1[2];
    #pragma unroll
    for (int kc = 0; kc < 2; ++kc)
        fa1[kc] = *(const bf16x8*)&aggr_bf[((size_t)b * NN + rn) * ED + kc * 32 + quad * 8];
    __syncthreads();

    {   // phase 1: C1[64 x 128]; wave w = m-tile w, all 8 j-tiles
        f32x4 acc[8];
        #pragma unroll
        for (int i = 0; i < 8; ++i) acc[i] = (f32x4){0.f, 0.f, 0.f, 0.f};
        #pragma unroll
        for (int t2 = 0; t2 < 8; ++t2) {
            #pragma unroll
            for (int kc = 0; kc < 2; ++kc) {
                const bf16x8 fbw = *(const bf16x8*)&W1Tl[(t2 * 16 + m) * 64 + kc * 32 + quad * 8];
                acc[t2] = __builtin_amdgcn_mfma_f32_16x16x32_bf16(fa1[kc], fbw, acc[t2], 0, 0, 0);
            }
        }
        float sa_r[4], dg_r[4];
        #pragma unroll
        for (int r = 0; r < 4; ++r) {
            const int row = w * 16 + quad * 4 + r;
            sa_r[r] = sdl[row]; dg_r[r] = ddl[row];
        }
        #pragma unroll
        for (int t2 = 0; t2 < 8; ++t2) {
            const int j = t2 * 16 + m;
            const float u = uL[j], v = vL[j], bb = bbL[j];
            const float sc = scL[j], sh = shL[j];
            #pragma unroll
            for (int r = 0; r < 4; ++r) {
                const float h1 = acc[t2][r] + sa_r[r] * u + dg_r[r] * v + bb;
                pb[(w * 16 + quad * 4 + r) * 136 + j] = f2bf(fmaxf(h1 * sc + sh, 0.f));
            }
        }
    }
    __syncthreads();
    {   // phase 2: C2[64 x 64]; wave w = m-tile w, all 4 n-tiles
        f32x4 acc2[4];
        #pragma unroll
        for (int i = 0; i < 4; ++i) acc2[i] = (f32x4){0.f, 0.f, 0.f, 0.f};
        #pragma unroll
        for (int kc = 0; kc < 4; ++kc) {
            const bf16x8 fa = *(const bf16x8*)&pb[(w * 16 + m) * 136 + kc * 32 + quad * 8];
            #pragma unroll
            for (int t2 = 0; t2 < 4; ++t2) {
                const bf16x8 fbw = *(const bf16x8*)&W2Tl[(t2 * 16 + m) * 128 + kc * 32 + quad * 8];
                acc2[t2] = __builtin_amdgcn_mfma_f32_16x16x32_bf16(fa, fbw, acc2[t2], 0, 0, 0);
            }
        }
        #pragma unroll
        for (int t2 = 0; t2 < 4; ++t2) {
            const int c = t2 * 16 + m;
            const float bb2 = b2l[c];
            #pragma unroll
            for (int r = 0; r < 4; ++r) {
                const int row = w * 16 + quad * 4 + r;
                const int n = n0 + row;
                if (n < NN) {
                    const size_t idx = ((size_t)b * NN + n) * ED + c;
                    float o = acc2[t2][r] + bb2;
                    if (last) outf[idx] = o;
                    else outh[idx] = __float2half(fmaxf(o, 0.f));
                }
            }
        }
    }
}

// ---------------- launch ----------------

extern "C" void kernel_launch(void* const* d_in, const int* in_sizes, int n_in,
                              void* d_out, int out_size, void* d_ws, size_t ws_size,
                              hipStream_t stream) {
    const float* x     = (const float*)d_in[0];
    const int*   ei    = (const int*)d_in[1];
    const float* eattr = (const float*)d_in[2];
    const float* inW   = (const float*)d_in[3];
    const float* inb   = (const float*)d_in[4];
    const float* edgeW = (const float*)d_in[5];
    const float* edgeb = (const float*)d_in[6];
    const float* W1    = (const float*)d_in[7];
    const float* b1    = (const float*)d_in[8];
    const float* gamma = (const float*)d_in[9];
    const float* beta  = (const float*)d_in[10];
    const float* W2    = (const float*)d_in[11];
    const float* b2    = (const float*)d_in[12];
    float* out = (float*)d_out;

    // workspace layout (~48 MiB)
    float* s_attr = (float*)d_ws;                               // B*N f
    int*   cnt    = (int*)(s_attr + NB * NN);                   // B*N i (deg)
    int*   rcnt   = cnt + NB * NN;                              // 128 i
    uint2* stage  = (uint2*)(rcnt + 128);                       // 128*SCAP uint2 (11.5 MB)
    unsigned int* bucket = (unsigned int*)(stage + (size_t)NB * NRANGE * SCAP); // B*N*CAP u32 (15.36 MB)
    short* aggr_bf = (short*)(bucket + (size_t)NB * NN * CAP);  // B*N*64 bf16 (10.24 MB)
    __half* hh    = (__half*)(aggr_bf + (size_t)NB * NN * ED);  // B*N*64 fp16 (10.24 MB)
    short* W1T    = (short*)(hh + (size_t)NB * NN * ED);        // 3*8192 bf16
    short* W2T    = W1T + 3 * 8192;                             // 3*8192 bf16
    float* uv_all = (float*)(W2T + 3 * 8192);                   // 3*256 f
    float* stats  = uv_all + 3 * 256;                           // 3*1024 f

    hipMemsetAsync(cnt, 0, ((size_t)NB * NN + 128) * sizeof(int), stream);

    k_compact<<<dim3((NE + 2047) / 2048, NB), 256, 0, stream>>>(ei, eattr, stage, rcnt);
    k_scatter<<<NB * NRANGE, 256, 0, stream>>>(stage, rcnt, cnt, bucket);
    k_in<<<dim3(NN * ED / 256, NB), 256, 0, stream>>>(x, inW, inb, hh);
    k_prep<<<3, 256, 0, stream>>>(W1, W2, edgeW, edgeb, W1T, W2T, uv_all, stats);

    const int nblk1 = NB * (NN / 16);                 // 5000
    const int nblk2 = 8 * (((NN + 63) / 64 + 1) / 2); // 1256, t guard inside
    for (int l = 0; l < 3; ++l) {
        k_aggr_stats<<<nblk1, 256, 0, stream>>>(hh, bucket, cnt,
            W1T + l * 8192, b1 + l * H2, uv_all + l * 256,
            aggr_bf, s_attr, stats + l * 1024, (l == 0) ? 1 : 0);
        k_mlp_out<<<nblk2, 256, 0, stream>>>(aggr_bf, s_attr, cnt,
            W1T + l * 8192, W2T + l * 8192, b1 + l * H2, uv_all + l * 256,
            stats + l * 1024, gamma + l * H2, beta + l * H2, b2 + l * ED,
            hh, out, (l == 2) ? 1 : 0);
    }
}

// Round 11
// 372.024 us; speedup vs baseline: 1.0741x; 1.0741x over previous
//
#include <hip/hip_runtime.h>
#include <hip/hip_bf16.h>
#include <hip/hip_fp16.h>

#define NB 4
#define NN 20000
#define NE 320000
#define IND 21
#define ED 64
#define H2 128
#define CAP 48
#define NRANGE 32
#define RNODES 625       // 32 * 625 = 20000
#define BINCAP 160       // compact LDS bin capacity (exp 64, 12 sigma)
#define SCAP 11264       // staging cap per (graph,range): exp 10000, 12 sigma
#define BN_EPS 1e-5f

typedef __attribute__((ext_vector_type(8))) short bf16x8;
typedef __attribute__((ext_vector_type(4))) float f32x4;

__device__ __forceinline__ short f2bf(float f) {
    unsigned u = __float_as_uint(f);
    u += 0x7fffu + ((u >> 16) & 1u);   // RNE
    return (short)(u >> 16);
}

__device__ __forceinline__ void add8(float* ac, const uint4 rv) {
    const float2 f0 = __half22float2(*(const __half2*)&rv.x);
    const float2 f1 = __half22float2(*(const __half2*)&rv.y);
    const float2 f2 = __half22float2(*(const __half2*)&rv.z);
    const float2 f3 = __half22float2(*(const __half2*)&rv.w);
    ac[0] += f0.x; ac[1] += f0.y; ac[2] += f1.x; ac[3] += f1.y;
    ac[4] += f2.x; ac[5] += f2.y; ac[6] += f3.x; ac[7] += f3.y;
}

// ---------------- setup kernels ----------------

// Phase A: coalesced pass over edges; LDS-bin into 32 dst-ranges (625 nodes);
// bulk-copy compact records (lo = src|bf16attr, hi = dst) to staging.
__global__ __launch_bounds__(256) void k_compact(
    const int* __restrict__ ei, const float* __restrict__ eattr,
    uint2* __restrict__ stage, int* __restrict__ rcnt)
{
    __shared__ uint2 bins[NRANGE][BINCAP];   // 40 KB
    __shared__ int lcnt[NRANGE];
    __shared__ int lbase[NRANGE];
    const int b = blockIdx.y;
    const int e0 = blockIdx.x * 2048;
    const int tid = threadIdx.x;
    if (tid < NRANGE) lcnt[tid] = 0;
    __syncthreads();
    const int* srcp = ei + (size_t)b * 2 * NE;
    const int* dstp = srcp + NE;
    const float* ap = eattr + (size_t)b * NE;
    #pragma unroll
    for (int it = 0; it < 8; ++it) {
        const int e = e0 + it * 256 + tid;
        if (e < NE) {
            const int dst = dstp[e];
            const int src = srcp[e];
            const float a = ap[e];
            const int r = dst / RNODES;
            const unsigned lo = ((unsigned)src & 0xffffu) | (__float_as_uint(a) & 0xffff0000u);
            const int p = atomicAdd(&lcnt[r], 1);
            if (p < BINCAP) bins[r][p] = make_uint2(lo, (unsigned)dst);
        }
    }
    __syncthreads();
    if (tid < NRANGE) lbase[tid] = atomicAdd(&rcnt[b * NRANGE + tid], min(lcnt[tid], BINCAP));
    __syncthreads();
    for (int r = 0; r < NRANGE; ++r) {
        const int c = min(lcnt[r], BINCAP);
        uint2* dstg = stage + (size_t)(b * NRANGE + r) * SCAP + lbase[r];
        for (int i = tid; i < c; i += 256) dstg[i] = bins[r][i];
    }
}

// Phase B: SINGLE-WRITER scatter. One block per (graph,range): its bucket
// slice + cnt slice are touched by this block only -> lines live in one L2,
// written back once (R9: this removed the 47 MB write-through).
__global__ __launch_bounds__(256) void k_scatter(
    const uint2* __restrict__ stage, const int* __restrict__ rcnt,
    int* __restrict__ cnt, unsigned int* __restrict__ bucket)
{
    const int b = blockIdx.x >> 5;
    const int g = blockIdx.x & 31;
    const int count = min(rcnt[b * NRANGE + g], SCAP);
    const uint2* st = stage + (size_t)(b * NRANGE + g) * SCAP;
    for (int idx = threadIdx.x; idx < count; idx += 256) {
        const uint2 rec = st[idx];
        const int node = b * NN + (int)rec.y;
        const int p = atomicAdd(&cnt[node], 1);
        if (p < CAP) bucket[(size_t)node * CAP + p] = rec.x;
    }
}

// h0 = x @ inW + inb, stored fp16 (gather-only consumer)
__global__ __launch_bounds__(256) void k_in(
    const float* __restrict__ x, const float* __restrict__ inW,
    const float* __restrict__ inb, __half* __restrict__ h)
{
    const int b = blockIdx.y;
    const int t = blockIdx.x * 256 + threadIdx.x;
    const int n = t >> 6;
    const int c = t & 63;
    if (n >= NN) return;
    const float* xr = x + ((size_t)b * NN + n) * IND;
    float acc = inb[c];
    #pragma unroll
    for (int k = 0; k < IND; ++k) acc += xr[k] * inW[k * ED + c];
    h[((size_t)b * NN + n) * ED + c] = __float2half(acc);
}

// Per-layer weight conversion (bf16, B-fragment layout), uv fold, stats zero.
__global__ __launch_bounds__(256) void k_prep(
    const float* __restrict__ W1, const float* __restrict__ W2,
    const float* __restrict__ edgeW, const float* __restrict__ edgeb,
    short* __restrict__ W1T, short* __restrict__ W2T,
    float* __restrict__ uv_all, float* __restrict__ stats_all)
{
    const int l = blockIdx.x;
    const int tid = threadIdx.x;
    ((float4*)(stats_all + l * 1024))[tid] = make_float4(0.f, 0.f, 0.f, 0.f);
    for (int i = tid; i < H2 * ED; i += 256) {
        const int j = i >> 6, k = i & 63;
        W1T[l * 8192 + i] = f2bf(W1[(size_t)l * H2 * H2 + k * H2 + j]);
    }
    for (int i = tid; i < ED * H2; i += 256) {
        const int c = i >> 7, k = i & 127;
        W2T[l * 8192 + i] = f2bf(W2[(size_t)l * H2 * ED + k * ED + c]);
    }
    if (tid < H2) {
        float u = 0.f, v = 0.f;
        for (int k = 0; k < ED; ++k) {
            const float w = W1[(size_t)l * H2 * H2 + (ED + k) * H2 + tid];
            u += edgeW[l * ED + k] * w;
            v += edgeb[l * ED + k] * w;
        }
        uv_all[l * 256 + tid] = u;
        uv_all[l * 256 + H2 + tid] = v;
    }
}

// ---------------- per-layer kernels ----------------

// FUSED: fp16 gather (8 lanes x 16B per node, 8-deep unroll) + attr-sum +
// bf16 aggr write + MFMA W1-top GEMM + BN stats. 32 nodes/block (R9 struct).
__global__ __launch_bounds__(256) void k_aggr_stats(
    const __half* __restrict__ h, const unsigned int* __restrict__ bucket,
    const int* __restrict__ cnt_arr, const short* __restrict__ W1Tl,
    const float* __restrict__ b1l, const float* __restrict__ uv_l,
    short* __restrict__ aggr_bf, float* __restrict__ s_attr,
    float* __restrict__ stats_l, int write_sattr)
{
    __shared__ short w1t[H2 * 72];    // 18 KB, padded stride 72
    __shared__ short atb[32 * 72];    // 4.5 KB
    __shared__ float sdl[32], ddl[32];
    __shared__ float uL[H2], vL[H2], bbL[H2];
    const int tid = threadIdx.x;
    const int g = blockIdx.x & 7;
    const int b = g >> 1;
    const int t = ((int)blockIdx.x >> 3) * 2 + (g & 1);
    if (t >= NN / 32) return;
    const int n0 = t * 32;

    for (int i = tid; i < 1024; i += 256)
        *(uint4*)&w1t[(i >> 3) * 72 + (i & 7) * 8] = ((const uint4*)W1Tl)[i];
    if (tid < H2) { uL[tid] = uv_l[tid]; vL[tid] = uv_l[H2 + tid]; bbL[tid] = b1l[tid]; }

    // gather: 8 lanes per node, 8 fp16 channels (16B) each; 8-edge unroll
    {
        const int node = n0 + (tid >> 3);
        const int q = tid & 7;
        const int cntraw = cnt_arr[b * NN + node];
        const int cnt = min(cntraw, CAP);
        const unsigned int* row = bucket + (size_t)(b * NN + node) * CAP;
        const __half* hp = h + (size_t)b * NN * ED + q * 8;
        float ac[8];
        #pragma unroll
        for (int i = 0; i < 8; ++i) ac[i] = 0.f;
        float sa = 0.f;
        int j = 0;
        for (; j + 8 <= cnt; j += 8) {
            const uint4 sA = *(const uint4*)(row + j);
            const uint4 sB = *(const uint4*)(row + j + 4);
            const uint4 r0 = *(const uint4*)(hp + (size_t)(sA.x & 0xffffu) * ED);
            const uint4 r1 = *(const uint4*)(hp + (size_t)(sA.y & 0xffffu) * ED);
            const uint4 r2 = *(const uint4*)(hp + (size_t)(sA.z & 0xffffu) * ED);
            const uint4 r3 = *(const uint4*)(hp + (size_t)(sA.w & 0xffffu) * ED);
            const uint4 r4 = *(const uint4*)(hp + (size_t)(sB.x & 0xffffu) * ED);
            const uint4 r5 = *(const uint4*)(hp + (size_t)(sB.y & 0xffffu) * ED);
            const uint4 r6 = *(const uint4*)(hp + (size_t)(sB.z & 0xffffu) * ED);
            const uint4 r7 = *(const uint4*)(hp + (size_t)(sB.w & 0xffffu) * ED);
            sa += __uint_as_float(sA.x & 0xffff0000u) + __uint_as_float(sA.y & 0xffff0000u)
                + __uint_as_float(sA.z & 0xffff0000u) + __uint_as_float(sA.w & 0xffff0000u)
                + __uint_as_float(sB.x & 0xffff0000u) + __uint_as_float(sB.y & 0xffff0000u)
                + __uint_as_float(sB.z & 0xffff0000u) + __uint_as_float(sB.w & 0xffff0000u);
            add8(ac, r0); add8(ac, r1); add8(ac, r2); add8(ac, r3);
            add8(ac, r4); add8(ac, r5); add8(ac, r6); add8(ac, r7);
        }
        for (; j + 4 <= cnt; j += 4) {
            const uint4 ss = *(const uint4*)(row + j);
            const uint4 r0 = *(const uint4*)(hp + (size_t)(ss.x & 0xffffu) * ED);
            const uint4 r1 = *(const uint4*)(hp + (size_t)(ss.y & 0xffffu) * ED);
            const uint4 r2 = *(const uint4*)(hp + (size_t)(ss.z & 0xffffu) * ED);
            const uint4 r3 = *(const uint4*)(hp + (size_t)(ss.w & 0xffffu) * ED);
            sa += __uint_as_float(ss.x & 0xffff0000u) + __uint_as_float(ss.y & 0xffff0000u)
                + __uint_as_float(ss.z & 0xffff0000u) + __uint_as_float(ss.w & 0xffff0000u);
            add8(ac, r0); add8(ac, r1); add8(ac, r2); add8(ac, r3);
        }
        for (; j < cnt; ++j) {
            const unsigned e = row[j];
            sa += __uint_as_float(e & 0xffff0000u);
            const uint4 r0 = *(const uint4*)(hp + (size_t)(e & 0xffffu) * ED);
            add8(ac, r0);
        }
        uint4 pk;
        pk.x = (unsigned short)f2bf(ac[0]) | ((unsigned int)(unsigned short)f2bf(ac[1]) << 16);
        pk.y = (unsigned short)f2bf(ac[2]) | ((unsigned int)(unsigned short)f2bf(ac[3]) << 16);
        pk.z = (unsigned short)f2bf(ac[4]) | ((unsigned int)(unsigned short)f2bf(ac[5]) << 16);
        pk.w = (unsigned short)f2bf(ac[6]) | ((unsigned int)(unsigned short)f2bf(ac[7]) << 16);
        *(uint4*)&atb[(tid >> 3) * 72 + q * 8] = pk;
        *(uint4*)&aggr_bf[((size_t)b * NN + node) * ED + q * 8] = pk;
        if (q == 0) {
            sdl[tid >> 3] = sa;
            ddl[tid >> 3] = (float)cntraw;
            if (write_sattr) s_attr[b * NN + node] = sa;
        }
    }
    __syncthreads();

    // MFMA: C[32 nodes x 128 j]; wave w: m-tile (w&1), j-tiles (w>>1)*4..+3
    const int l = tid & 63;
    const int w = tid >> 6;
    const int m = l & 15, quad = l >> 4;
    const int mt = w & 1;
    const int jb = (w >> 1) * 4;
    f32x4 acc[4];
    #pragma unroll
    for (int i = 0; i < 4; ++i) acc[i] = (f32x4){0.f, 0.f, 0.f, 0.f};
    #pragma unroll
    for (int kc = 0; kc < 2; ++kc) {
        const bf16x8 fa = *(const bf16x8*)&atb[(mt * 16 + m) * 72 + kc * 32 + quad * 8];
        #pragma unroll
        for (int t2 = 0; t2 < 4; ++t2) {
            const bf16x8 fb = *(const bf16x8*)&w1t[((jb + t2) * 16 + m) * 72 + kc * 32 + quad * 8];
            acc[t2] = __builtin_amdgcn_mfma_f32_16x16x32_bf16(fa, fb, acc[t2], 0, 0, 0);
        }
    }
    float sa_r[4], dg_r[4];
    #pragma unroll
    for (int r = 0; r < 4; ++r) {
        const int row = mt * 16 + quad * 4 + r;
        sa_r[r] = sdl[row]; dg_r[r] = ddl[row];
    }
    #pragma unroll
    for (int t2 = 0; t2 < 4; ++t2) {
        const int j = (jb + t2) * 16 + m;
        const float u = uL[j], v = vL[j], bb = bbL[j];
        float ls = 0.f, lq = 0.f;
        #pragma unroll
        for (int r = 0; r < 4; ++r) {
            const float h1 = acc[t2][r] + sa_r[r] * u + dg_r[r] * v + bb;
            ls += h1; lq += h1 * h1;
        }
        ls += __shfl_xor(ls, 16); ls += __shfl_xor(ls, 32);
        lq += __shfl_xor(lq, 16); lq += __shfl_xor(lq, 32);
        if (l < 16) {
            atomicAdd(&stats_l[b * H2 + j], ls);
            atomicAdd(&stats_l[NB * H2 + b * H2 + j], lq);
        }
    }
}

// Out pass, 64 nodes/block, fused BN finalize (R9 struct):
// MFMA W1-top GEMM -> BN+ReLU -> MFMA W2 GEMM -> out (fp16 h or fp32 d_out).
__global__ __launch_bounds__(256) void k_mlp_out(
    const short* __restrict__ aggr_bf, const float* __restrict__ s_attr,
    const int* __restrict__ cnt_arr, const short* __restrict__ W1Tl,
    const short* __restrict__ W2Tl, const float* __restrict__ b1l,
    const float* __restrict__ uv_l, const float* __restrict__ stats_l,
    const float* __restrict__ gamma_l, const float* __restrict__ beta_l,
    const float* __restrict__ b2l, __half* __restrict__ outh,
    float* __restrict__ outf, int last)
{
    __shared__ short wt[H2 * 72];     // 18 KB: W1T (128x72) then W2T (64x136)
    __shared__ short ab[64 * 72];     // 9 KB
    __shared__ short pb[64 * 136];    // 17 KB
    __shared__ float sdl[64], ddl[64];
    __shared__ float uL[H2], vL[H2], bbL[H2], scL[H2], shL[H2];
    const int tid = threadIdx.x;
    const int g = blockIdx.x & 7;
    const int b = g >> 1;
    const int t = ((int)blockIdx.x >> 3) * 2 + (g & 1);
    if (t >= (NN + 63) / 64) return;
    const int n0 = t * 64;

    for (int i = tid; i < 1024; i += 256)
        *(uint4*)&wt[(i >> 3) * 72 + (i & 7) * 8] = ((const uint4*)W1Tl)[i];
    for (int i = tid; i < 512; i += 256)
        *(uint4*)&ab[(i >> 3) * 72 + (i & 7) * 8] =
            ((const uint4*)(aggr_bf + ((size_t)b * NN + n0) * ED))[i];
    if (tid < 64) sdl[tid] = s_attr[b * NN + n0 + tid];
    else if (tid < 128) ddl[tid - 64] = (float)cnt_arr[b * NN + n0 + tid - 64];
    if (tid < H2) {
        const int j = tid;
        const float mm = stats_l[b * H2 + j] * (1.f / NN);
        const float var = fmaxf(stats_l[NB * H2 + b * H2 + j] * (1.f / NN) - mm * mm, 0.f);
        const float rs = rsqrtf(var + BN_EPS);
        const float sc = gamma_l[j] * rs;
        scL[j] = sc;
        shL[j] = beta_l[j] - mm * sc;
        uL[j] = uv_l[j]; vL[j] = uv_l[H2 + j]; bbL[j] = b1l[j];
    }
    __syncthreads();

    const int l = tid & 63;
    const int w = tid >> 6;
    const int m = l & 15, quad = l >> 4;
    {   // phase 1: C1[64 x 128]; wave w = m-tile w, all 8 j-tiles
        f32x4 acc[8];
        #pragma unroll
        for (int i = 0; i < 8; ++i) acc[i] = (f32x4){0.f, 0.f, 0.f, 0.f};
        #pragma unroll
        for (int kc = 0; kc < 2; ++kc) {
            const bf16x8 fa = *(const bf16x8*)&ab[(w * 16 + m) * 72 + kc * 32 + quad * 8];
            #pragma unroll
            for (int t2 = 0; t2 < 8; ++t2) {
                const bf16x8 fb = *(const bf16x8*)&wt[(t2 * 16 + m) * 72 + kc * 32 + quad * 8];
                acc[t2] = __builtin_amdgcn_mfma_f32_16x16x32_bf16(fa, fb, acc[t2], 0, 0, 0);
            }
        }
        float sa_r[4], dg_r[4];
        #pragma unroll
        for (int r = 0; r < 4; ++r) {
            const int row = w * 16 + quad * 4 + r;
            sa_r[r] = sdl[row]; dg_r[r] = ddl[row];
        }
        #pragma unroll
        for (int t2 = 0; t2 < 8; ++t2) {
            const int j = t2 * 16 + m;
            const float u = uL[j], v = vL[j], bb = bbL[j];
            const float sc = scL[j], sh = shL[j];
            #pragma unroll
            for (int r = 0; r < 4; ++r) {
                const float h1 = acc[t2][r] + sa_r[r] * u + dg_r[r] * v + bb;
                pb[(w * 16 + quad * 4 + r) * 136 + j] = f2bf(fmaxf(h1 * sc + sh, 0.f));
            }
        }
    }
    __syncthreads();
    for (int i = tid; i < 1024; i += 256)
        *(uint4*)&wt[(i >> 4) * 136 + (i & 15) * 8] = ((const uint4*)W2Tl)[i];
    __syncthreads();
    {   // phase 2: C2[64 x 64]; wave w = m-tile w, all 4 n-tiles
        f32x4 acc2[4];
        #pragma unroll
        for (int i = 0; i < 4; ++i) acc2[i] = (f32x4){0.f, 0.f, 0.f, 0.f};
        #pragma unroll
        for (int kc = 0; kc < 4; ++kc) {
            const bf16x8 fa = *(const bf16x8*)&pb[(w * 16 + m) * 136 + kc * 32 + quad * 8];
            #pragma unroll
            for (int t2 = 0; t2 < 4; ++t2) {
                const bf16x8 fb = *(const bf16x8*)&wt[(t2 * 16 + m) * 136 + kc * 32 + quad * 8];
                acc2[t2] = __builtin_amdgcn_mfma_f32_16x16x32_bf16(fa, fb, acc2[t2], 0, 0, 0);
            }
        }
        #pragma unroll
        for (int t2 = 0; t2 < 4; ++t2) {
            const int c = t2 * 16 + m;
            const float bb2 = b2l[c];
            #pragma unroll
            for (int r = 0; r < 4; ++r) {
                const int row = w * 16 + quad * 4 + r;
                const int n = n0 + row;
                if (n < NN) {
                    const size_t idx = ((size_t)b * NN + n) * ED + c;
                    float o = acc2[t2][r] + bb2;
                    if (last) outf[idx] = o;
                    else outh[idx] = __float2half(fmaxf(o, 0.f));
                }
            }
        }
    }
}

// ---------------- launch ----------------

extern "C" void kernel_launch(void* const* d_in, const int* in_sizes, int n_in,
                              void* d_out, int out_size, void* d_ws, size_t ws_size,
                              hipStream_t stream) {
    const float* x     = (const float*)d_in[0];
    const int*   ei    = (const int*)d_in[1];
    const float* eattr = (const float*)d_in[2];
    const float* inW   = (const float*)d_in[3];
    const float* inb   = (const float*)d_in[4];
    const float* edgeW = (const float*)d_in[5];
    const float* edgeb = (const float*)d_in[6];
    const float* W1    = (const float*)d_in[7];
    const float* b1    = (const float*)d_in[8];
    const float* gamma = (const float*)d_in[9];
    const float* beta  = (const float*)d_in[10];
    const float* W2    = (const float*)d_in[11];
    const float* b2    = (const float*)d_in[12];
    float* out = (float*)d_out;

    // workspace layout (~48 MiB)
    float* s_attr = (float*)d_ws;                               // B*N f
    int*   cnt    = (int*)(s_attr + NB * NN);                   // B*N i (deg)
    int*   rcnt   = cnt + NB * NN;                              // 128 i
    uint2* stage  = (uint2*)(rcnt + 128);                       // 128*SCAP uint2 (11.5 MB)
    unsigned int* bucket = (unsigned int*)(stage + (size_t)NB * NRANGE * SCAP); // B*N*CAP u32 (15.36 MB)
    short* aggr_bf = (short*)(bucket + (size_t)NB * NN * CAP);  // B*N*64 bf16 (10.24 MB)
    __half* hh    = (__half*)(aggr_bf + (size_t)NB * NN * ED);  // B*N*64 fp16 (10.24 MB)
    short* W1T    = (short*)(hh + (size_t)NB * NN * ED);        // 3*8192 bf16
    short* W2T    = W1T + 3 * 8192;                             // 3*8192 bf16
    float* uv_all = (float*)(W2T + 3 * 8192);                   // 3*256 f
    float* stats  = uv_all + 3 * 256;                           // 3*1024 f

    hipMemsetAsync(cnt, 0, ((size_t)NB * NN + 128) * sizeof(int), stream);

    k_compact<<<dim3((NE + 2047) / 2048, NB), 256, 0, stream>>>(ei, eattr, stage, rcnt);
    k_scatter<<<NB * NRANGE, 256, 0, stream>>>(stage, rcnt, cnt, bucket);
    k_in<<<dim3(NN * ED / 256, NB), 256, 0, stream>>>(x, inW, inb, hh);
    k_prep<<<3, 256, 0, stream>>>(W1, W2, edgeW, edgeb, W1T, W2T, uv_all, stats);

    const int nblk1 = 8 * ((NN / 32 + 1) / 2);        // 2504, t guard inside
    const int nblk2 = 8 * (((NN + 63) / 64 + 1) / 2); // 1256, t guard inside
    for (int l = 0; l < 3; ++l) {
        k_aggr_stats<<<nblk1, 256, 0, stream>>>(hh, bucket, cnt,
            W1T + l * 8192, b1 + l * H2, uv_all + l * 256,
            aggr_bf, s_attr, stats + l * 1024, (l == 0) ? 1 : 0);
        k_mlp_out<<<nblk2, 256, 0, stream>>>(aggr_bf, s_attr, cnt,
            W1T + l * 8192, W2T + l * 8192, b1 + l * H2, uv_all + l * 256,
            stats + l * 1024, gamma + l * H2, beta + l * H2, b2 + l * ED,
            hh, out, (l == 2) ? 1 : 0);
    }
}